// Round 1
// baseline (606.804 us; speedup 1.0000x reference)
//
#include <hip/hip_runtime.h>

// ZBL pair potential + segment-sum into NUM_SYSTEMS bins.
// Inputs (setup_inputs order):
//  0: local_d_ij               float32 [16M]
//  1: radii_table              float32 [97]
//  2: local_pair_indices       int32   [2, 16M]  (row 0 = idx_i, row 1 = idx_j)
//  3: atomic_numbers           int32   [1M]
//  4: atomic_subsystem_indices int32   [1M]
// Output: float32 [10000] per-system energy.

constexpr int MAXZ = 97;

constexpr double LOG2E_D = 1.4426950408889634;
constexpr float A_INV = (float)(1.0 / (0.8854 * 0.0529177210903));
constexpr float C1 = (float)(-3.2    * LOG2E_D);
constexpr float C2 = (float)(-0.9423 * LOG2E_D);
constexpr float C3 = (float)(-0.4029 * LOG2E_D);
constexpr float C4 = (float)(-0.2016 * LOG2E_D);
constexpr float COUL = 138.9354576f;

__global__ void zero_kernel(float* __restrict__ out, int n) {
    int i = blockIdx.x * blockDim.x + threadIdx.x;
    if (i < n) out[i] = 0.0f;
}

// packed[i] = z | (seg << 8)   (z < 97 fits in 8 bits, seg < 10000 fits in 24)
__global__ void pack_kernel(const int* __restrict__ z,
                            const int* __restrict__ seg,
                            unsigned int* __restrict__ packed, int n) {
    int i = blockIdx.x * blockDim.x + threadIdx.x;
    if (i < n)
        packed[i] = (unsigned int)z[i] | ((unsigned int)seg[i] << 8);
}

template <bool PACKED>
__global__ __launch_bounds__(256)
void zbl_kernel(const float* __restrict__ d_ij,
                const float* __restrict__ radii,
                const int* __restrict__ idx_i,
                const int* __restrict__ idx_j,
                const unsigned int* __restrict__ packed,
                const int* __restrict__ atomz,
                const int* __restrict__ subsys,
                float* __restrict__ out,
                int nchunk) {
    // LDS tables: radius[z] and z^0.23 (z in [0,96]).
    __shared__ float s_r[128];
    __shared__ float s_zp[128];
    int t = threadIdx.x;
    if (t < 128) {
        s_r[t] = (t < MAXZ) ? radii[t] : 0.0f;
        float zf = (float)t;
        // z^0.23 = exp2(0.23*log2(z)); t==0 -> exp2(-inf)=0, unused (z>=1).
        s_zp[t] = __builtin_exp2f(0.23f * __builtin_log2f(zf));
    }
    __syncthreads();

    int chunk = blockIdx.x * blockDim.x + threadIdx.x;
    if (chunk >= nchunk) return;

    int4 ii = reinterpret_cast<const int4*>(idx_i)[chunk];
    int4 jj = reinterpret_cast<const int4*>(idx_j)[chunk];
    float4 dd = reinterpret_cast<const float4*>(d_ij)[chunk];

    int iv[4] = {ii.x, ii.y, ii.z, ii.w};
    int jv[4] = {jj.x, jj.y, jj.z, jj.w};
    float dv[4] = {dd.x, dd.y, dd.z, dd.w};

#pragma unroll
    for (int k = 0; k < 4; ++k) {
        int i = iv[k];
        int j = jv[k];
        float d = dv[k];
        if (i < j) {  // mask check BEFORE any gather — halves L2 gather traffic
            int zi, zj, seg;
            if (PACKED) {
                unsigned int pi = packed[i];
                unsigned int pj = packed[j];
                zi = (int)(pi & 0xFFu);
                zj = (int)(pj & 0xFFu);
                seg = (int)(pi >> 8);
            } else {
                zi = atomz[i];
                zj = atomz[j];
                seg = subsys[i];
            }
            float rsum = s_r[zi] + s_r[zj];
            if (d < rsum) {  // phi==0 otherwise -> zero contribution, skip all math
                float dA = d * (s_zp[zi] + s_zp[zj]) * A_INV;
                float f = 0.1818f  * __builtin_exp2f(C1 * dA)
                        + 0.5099f  * __builtin_exp2f(C2 * dA)
                        + 0.2802f  * __builtin_exp2f(C3 * dA)
                        + 0.02817f * __builtin_exp2f(C4 * dA);
                float tt = d * __builtin_amdgcn_rcpf(rsum);      // d/rsum in [0,1)
                // cos(pi*t) = v_cos(t/2)  (v_cos_f32 input is in revolutions)
                float phi = 0.5f * (__builtin_amdgcn_cosf(0.5f * tt) + 1.0f);
                float zif = (float)zi, zjf = (float)zj;
                float e = f * phi * (COUL * zif * zjf) * __builtin_amdgcn_rcpf(d);
                atomicAdd(out + seg, e);
            }
        }
    }
}

extern "C" void kernel_launch(void* const* d_in, const int* in_sizes, int n_in,
                              void* d_out, int out_size, void* d_ws, size_t ws_size,
                              hipStream_t stream) {
    const float* d_ij  = (const float*)d_in[0];
    const float* radii = (const float*)d_in[1];
    const int* pairs   = (const int*)d_in[2];
    const int* atomz   = (const int*)d_in[3];
    const int* subsys  = (const int*)d_in[4];
    float* out = (float*)d_out;

    const int n_edges = in_sizes[2] / 2;   // 16,000,000
    const int n_atoms = in_sizes[3];       // 1,000,000
    const int* idx_i = pairs;
    const int* idx_j = pairs + n_edges;

    // d_out is poisoned before every launch — zero it ourselves.
    zero_kernel<<<(out_size + 255) / 256, 256, 0, stream>>>(out, out_size);

    const int nchunk = n_edges / 4;  // 16M divisible by 4
    const int blocks = (nchunk + 255) / 256;

    const bool use_packed = ws_size >= (size_t)n_atoms * sizeof(unsigned int);
    if (use_packed) {
        unsigned int* packed = (unsigned int*)d_ws;
        pack_kernel<<<(n_atoms + 255) / 256, 256, 0, stream>>>(atomz, subsys,
                                                               packed, n_atoms);
        zbl_kernel<true><<<blocks, 256, 0, stream>>>(
            d_ij, radii, idx_i, idx_j, packed, atomz, subsys, out, nchunk);
    } else {
        zbl_kernel<false><<<blocks, 256, 0, stream>>>(
            d_ij, radii, idx_i, idx_j, nullptr, atomz, subsys, out, nchunk);
    }
}

// Round 3
// 312.669 us; speedup vs baseline: 1.9407x; 1.9407x over previous
//
#include <hip/hip_runtime.h>

// ZBL pair potential + segment-sum into NUM_SYSTEMS bins.
// Inputs (setup_inputs order):
//  0: local_d_ij               float32 [16M]
//  1: radii_table              float32 [97]
//  2: local_pair_indices       int32   [2, 16M]  (row 0 = idx_i, row 1 = idx_j)
//  3: atomic_numbers           int32   [1M]
//  4: atomic_subsystem_indices int32   [1M]
// Output: float32 [10000] per-system energy.
//
// R2 design: global fp32 atomics on gfx950 resolve at the fabric/memory side
// (R1 evidence: WRITE_SIZE=149MB for a 40KB output, VALUBusy 7%) -> replace
// with per-block LDS histograms + atomic-free tree reduction.
// R3 fix: __builtin_nontemporal_* requires clang ext_vector types, not
// HIP_vector_type structs.

constexpr int MAXZ = 97;
constexpr int NBINS_PAD = 10240;   // 10000 bins padded for float4 flush
constexpr int NREP = 512;          // histogram replicas = grid of main kernel
constexpr int NPART = 32;          // first-stage reduction fan-in groups

constexpr double LOG2E_D = 1.4426950408889634;
constexpr float A_INV = (float)(1.0 / (0.8854 * 0.0529177210903));
constexpr float C1 = (float)(-3.2    * LOG2E_D);
constexpr float C2 = (float)(-0.9423 * LOG2E_D);
constexpr float C3 = (float)(-0.4029 * LOG2E_D);
constexpr float C4 = (float)(-0.2016 * LOG2E_D);
constexpr float COUL = 138.9354576f;

typedef int   iv4 __attribute__((ext_vector_type(4)));
typedef float fv4 __attribute__((ext_vector_type(4)));

__global__ void zero_kernel(float* __restrict__ out, int n) {
    int i = blockIdx.x * blockDim.x + threadIdx.x;
    if (i < n) out[i] = 0.0f;
}

// packed[i] = z | (seg << 8)   (z < 97 fits in 8 bits, seg < 10000 fits in 24)
__global__ void pack_kernel(const int* __restrict__ z,
                            const int* __restrict__ seg,
                            unsigned int* __restrict__ packed, int n) {
    int i = blockIdx.x * blockDim.x + threadIdx.x;
    if (i < n)
        packed[i] = (unsigned int)z[i] | ((unsigned int)seg[i] << 8);
}

// ---------------- main path: LDS histogram, no global atomics ---------------

__global__ __launch_bounds__(1024)
void zbl_hist_kernel(const float* __restrict__ d_ij,
                     const float* __restrict__ radii,
                     const int* __restrict__ idx_i,
                     const int* __restrict__ idx_j,
                     const unsigned int* __restrict__ packed,
                     float* __restrict__ rep,     // [NREP][NBINS_PAD]
                     int nchunk) {
    __shared__ float s_hist[NBINS_PAD];  // 40 KiB
    __shared__ float s_r[128];
    __shared__ float s_zp[128];
    const int t = threadIdx.x;

    for (int b = t; b < NBINS_PAD; b += 1024) s_hist[b] = 0.0f;
    if (t < 128) {
        s_r[t] = (t < MAXZ) ? radii[t] : 0.0f;
        // z^0.23 = exp2(0.23*log2(z)); t==0 -> 0, unused (z>=1).
        s_zp[t] = __builtin_exp2f(0.23f * __builtin_log2f((float)t));
    }
    __syncthreads();

    const int stride = gridDim.x * blockDim.x;
    for (int c = blockIdx.x * blockDim.x + t; c < nchunk; c += stride) {
        // Non-temporal: don't let the 192MB stream evict the 4MB gather table
        // from L2.
        iv4 ii = __builtin_nontemporal_load(
            reinterpret_cast<const iv4*>(idx_i) + c);
        iv4 jj = __builtin_nontemporal_load(
            reinterpret_cast<const iv4*>(idx_j) + c);
        fv4 dd = __builtin_nontemporal_load(
            reinterpret_cast<const fv4*>(d_ij) + c);

#pragma unroll
        for (int k = 0; k < 4; ++k) {
            int i = ii[k];
            int j = jj[k];
            float d = dd[k];
            if (i < j) {  // mask before gather — halves L2 gather traffic
                unsigned int pi = packed[i];
                unsigned int pj = packed[j];
                int zi = (int)(pi & 0xFFu);
                int zj = (int)(pj & 0xFFu);
                int seg = (int)(pi >> 8);
                float rsum = s_r[zi] + s_r[zj];
                if (d < rsum) {  // phi==0 otherwise
                    float dA = d * (s_zp[zi] + s_zp[zj]) * A_INV;
                    float f = 0.1818f  * __builtin_exp2f(C1 * dA)
                            + 0.5099f  * __builtin_exp2f(C2 * dA)
                            + 0.2802f  * __builtin_exp2f(C3 * dA)
                            + 0.02817f * __builtin_exp2f(C4 * dA);
                    float tt = d * __builtin_amdgcn_rcpf(rsum);  // in [0,1)
                    // cos(pi*t) = v_cos(t/2)  (v_cos input in revolutions)
                    float phi = 0.5f * (__builtin_amdgcn_cosf(0.5f * tt) + 1.0f);
                    float e = f * phi * (COUL * (float)zi * (float)zj)
                            * __builtin_amdgcn_rcpf(d);
                    atomicAdd(&s_hist[seg], e);  // LDS atomic — stays on-CU
                }
            }
        }
    }

    __syncthreads();
    // Flush histogram to this block's replica row (coalesced float4 stores).
    fv4* __restrict__ rp =
        reinterpret_cast<fv4*>(rep + (size_t)blockIdx.x * NBINS_PAD);
    const fv4* sh = reinterpret_cast<const fv4*>(s_hist);
    for (int q = t; q < NBINS_PAD / 4; q += 1024)
        __builtin_nontemporal_store(sh[q], rp + q);
}

// Stage 1: partial[s][bin] = sum over replica rows r = s, s+NPART, ...
__global__ __launch_bounds__(256)
void reduce1_kernel(const float* __restrict__ rep,
                    float* __restrict__ partial) {
    int bin = blockIdx.x * 256 + threadIdx.x;
    int s = blockIdx.y;
    float acc = 0.0f;
    for (int r = s; r < NREP; r += NPART)
        acc += rep[(size_t)r * NBINS_PAD + bin];
    partial[(size_t)s * NBINS_PAD + bin] = acc;
}

// Stage 2: out[bin] = sum over NPART partials. Writes every bin (no zero pass).
__global__ __launch_bounds__(256)
void reduce2_kernel(const float* __restrict__ partial,
                    float* __restrict__ out, int out_size) {
    int bin = blockIdx.x * 256 + threadIdx.x;
    if (bin < out_size) {
        float acc = 0.0f;
        for (int s = 0; s < NPART; ++s)
            acc += partial[(size_t)s * NBINS_PAD + bin];
        out[bin] = acc;
    }
}

// ---------------- fallback path (R1): direct global atomics ----------------

template <bool PACKED>
__global__ __launch_bounds__(256)
void zbl_atomic_kernel(const float* __restrict__ d_ij,
                       const float* __restrict__ radii,
                       const int* __restrict__ idx_i,
                       const int* __restrict__ idx_j,
                       const unsigned int* __restrict__ packed,
                       const int* __restrict__ atomz,
                       const int* __restrict__ subsys,
                       float* __restrict__ out,
                       int nchunk) {
    __shared__ float s_r[128];
    __shared__ float s_zp[128];
    int t = threadIdx.x;
    if (t < 128) {
        s_r[t] = (t < MAXZ) ? radii[t] : 0.0f;
        s_zp[t] = __builtin_exp2f(0.23f * __builtin_log2f((float)t));
    }
    __syncthreads();

    int chunk = blockIdx.x * blockDim.x + threadIdx.x;
    if (chunk >= nchunk) return;

    iv4 ii = reinterpret_cast<const iv4*>(idx_i)[chunk];
    iv4 jj = reinterpret_cast<const iv4*>(idx_j)[chunk];
    fv4 dd = reinterpret_cast<const fv4*>(d_ij)[chunk];

#pragma unroll
    for (int k = 0; k < 4; ++k) {
        int i = ii[k];
        int j = jj[k];
        float d = dd[k];
        if (i < j) {
            int zi, zj, seg;
            if (PACKED) {
                unsigned int pi = packed[i];
                unsigned int pj = packed[j];
                zi = (int)(pi & 0xFFu);
                zj = (int)(pj & 0xFFu);
                seg = (int)(pi >> 8);
            } else {
                zi = atomz[i];
                zj = atomz[j];
                seg = subsys[i];
            }
            float rsum = s_r[zi] + s_r[zj];
            if (d < rsum) {
                float dA = d * (s_zp[zi] + s_zp[zj]) * A_INV;
                float f = 0.1818f  * __builtin_exp2f(C1 * dA)
                        + 0.5099f  * __builtin_exp2f(C2 * dA)
                        + 0.2802f  * __builtin_exp2f(C3 * dA)
                        + 0.02817f * __builtin_exp2f(C4 * dA);
                float tt = d * __builtin_amdgcn_rcpf(rsum);
                float phi = 0.5f * (__builtin_amdgcn_cosf(0.5f * tt) + 1.0f);
                float e = f * phi * (COUL * (float)zi * (float)zj)
                        * __builtin_amdgcn_rcpf(d);
                atomicAdd(out + seg, e);
            }
        }
    }
}

extern "C" void kernel_launch(void* const* d_in, const int* in_sizes, int n_in,
                              void* d_out, int out_size, void* d_ws, size_t ws_size,
                              hipStream_t stream) {
    const float* d_ij  = (const float*)d_in[0];
    const float* radii = (const float*)d_in[1];
    const int* pairs   = (const int*)d_in[2];
    const int* atomz   = (const int*)d_in[3];
    const int* subsys  = (const int*)d_in[4];
    float* out = (float*)d_out;

    const int n_edges = in_sizes[2] / 2;   // 16,000,000
    const int n_atoms = in_sizes[3];       // 1,000,000
    const int* idx_i = pairs;
    const int* idx_j = pairs + n_edges;
    const int nchunk = n_edges / 4;

    const size_t packed_bytes = (size_t)n_atoms * sizeof(unsigned int);
    const size_t rep_bytes = (size_t)NREP * NBINS_PAD * sizeof(float);
    const size_t part_bytes = (size_t)NPART * NBINS_PAD * sizeof(float);

    if (ws_size >= packed_bytes + rep_bytes + part_bytes) {
        unsigned int* packed = (unsigned int*)d_ws;
        float* rep = (float*)((char*)d_ws + packed_bytes);
        float* partial = (float*)((char*)d_ws + packed_bytes + rep_bytes);

        pack_kernel<<<(n_atoms + 255) / 256, 256, 0, stream>>>(atomz, subsys,
                                                               packed, n_atoms);
        zbl_hist_kernel<<<NREP, 1024, 0, stream>>>(
            d_ij, radii, idx_i, idx_j, packed, rep, nchunk);
        dim3 g1(NBINS_PAD / 256, NPART);
        reduce1_kernel<<<g1, 256, 0, stream>>>(rep, partial);
        reduce2_kernel<<<(out_size + 255) / 256, 256, 0, stream>>>(
            partial, out, out_size);
    } else {
        // Fallback: direct-atomic path (R1)
        zero_kernel<<<(out_size + 255) / 256, 256, 0, stream>>>(out, out_size);
        const int blocks = (nchunk + 255) / 256;
        if (ws_size >= packed_bytes) {
            unsigned int* packed = (unsigned int*)d_ws;
            pack_kernel<<<(n_atoms + 255) / 256, 256, 0, stream>>>(
                atomz, subsys, packed, n_atoms);
            zbl_atomic_kernel<true><<<blocks, 256, 0, stream>>>(
                d_ij, radii, idx_i, idx_j, packed, atomz, subsys, out, nchunk);
        } else {
            zbl_atomic_kernel<false><<<blocks, 256, 0, stream>>>(
                d_ij, radii, idx_i, idx_j, nullptr, atomz, subsys, out, nchunk);
        }
    }
}

// Round 4
// 311.285 us; speedup vs baseline: 1.9494x; 1.0044x over previous
//
#include <hip/hip_runtime.h>

// ZBL pair potential + segment-sum into NUM_SYSTEMS bins.
// Inputs (setup_inputs order):
//  0: local_d_ij               float32 [16M]
//  1: radii_table              float32 [97]
//  2: local_pair_indices       int32   [2, 16M]  (row 0 = idx_i, row 1 = idx_j)
//  3: atomic_numbers           int32   [1M]
//  4: atomic_subsystem_indices int32   [1M]
// Output: float32 [10000] per-system energy.
//
// R2: LDS histograms + tree reduction (global atomics were the R1 serializer:
//     WRITE_SIZE 149MB for a 40KB output).
// R4: latency-bound fix (R3: VALU 23%, HBM 17% — nothing busy). Gathers were
//     serialized inside exec-masked branches (2 outstanding/thread). Now: 8
//     edges/thread, all 16 gathers issued unconditionally up-front via
//     cndmask address select (masked lanes read packed[0] — hot line, free),
//     compute afterwards. 8x the memory-level parallelism.

constexpr int MAXZ = 97;
constexpr int NBINS_PAD = 10240;   // 10000 bins padded for float4 flush
constexpr int NREP = 512;          // histogram replicas = grid of main kernel
constexpr int NPART = 32;          // first-stage reduction fan-in groups

constexpr double LOG2E_D = 1.4426950408889634;
constexpr float A_INV = (float)(1.0 / (0.8854 * 0.0529177210903));
constexpr float C1 = (float)(-3.2    * LOG2E_D);
constexpr float C2 = (float)(-0.9423 * LOG2E_D);
constexpr float C3 = (float)(-0.4029 * LOG2E_D);
constexpr float C4 = (float)(-0.2016 * LOG2E_D);
constexpr float COUL = 138.9354576f;

typedef int   iv4 __attribute__((ext_vector_type(4)));
typedef float fv4 __attribute__((ext_vector_type(4)));

__global__ void zero_kernel(float* __restrict__ out, int n) {
    int i = blockIdx.x * blockDim.x + threadIdx.x;
    if (i < n) out[i] = 0.0f;
}

// packed[i] = z | (seg << 8)   (z < 97 fits in 8 bits, seg < 10000 fits in 24)
__global__ void pack_kernel(const int* __restrict__ z,
                            const int* __restrict__ seg,
                            unsigned int* __restrict__ packed, int n) {
    int i = blockIdx.x * blockDim.x + threadIdx.x;
    if (i < n)
        packed[i] = (unsigned int)z[i] | ((unsigned int)seg[i] << 8);
}

// Shared edge-energy math (tables in LDS).
__device__ __forceinline__ float zbl_energy(int zi, int zj, float d,
                                            const float* s_r,
                                            const float* s_zp,
                                            bool& pass) {
    float rsum = s_r[zi] + s_r[zj];
    pass = (d < rsum);
    if (!pass) return 0.0f;
    float dA = d * (s_zp[zi] + s_zp[zj]) * A_INV;
    float f = 0.1818f  * __builtin_exp2f(C1 * dA)
            + 0.5099f  * __builtin_exp2f(C2 * dA)
            + 0.2802f  * __builtin_exp2f(C3 * dA)
            + 0.02817f * __builtin_exp2f(C4 * dA);
    float tt = d * __builtin_amdgcn_rcpf(rsum);          // in [0,1)
    // cos(pi*t) = v_cos(t/2)  (v_cos input is in revolutions)
    float phi = 0.5f * (__builtin_amdgcn_cosf(0.5f * tt) + 1.0f);
    return f * phi * (COUL * (float)zi * (float)zj) * __builtin_amdgcn_rcpf(d);
}

// ---------------- main path: LDS histogram, no global atomics ---------------

__global__ __launch_bounds__(1024)
void zbl_hist_kernel(const float* __restrict__ d_ij,
                     const float* __restrict__ radii,
                     const int* __restrict__ idx_i,
                     const int* __restrict__ idx_j,
                     const unsigned int* __restrict__ packed,
                     float* __restrict__ rep,     // [NREP][NBINS_PAD]
                     int n_edges) {
    __shared__ float s_hist[NBINS_PAD];  // 40 KiB
    __shared__ float s_r[128];
    __shared__ float s_zp[128];
    const int t = threadIdx.x;

    for (int b = t; b < NBINS_PAD; b += 1024) s_hist[b] = 0.0f;
    if (t < 128) {
        s_r[t] = (t < MAXZ) ? radii[t] : 0.0f;
        // z^0.23 = exp2(0.23*log2(z)); t==0 -> 0, unused (z>=1).
        s_zp[t] = __builtin_exp2f(0.23f * __builtin_log2f((float)t));
    }
    __syncthreads();

    const int ngrp = n_edges >> 3;   // groups of 8 edges
    const int stride = gridDim.x * blockDim.x;
    for (int g = blockIdx.x * blockDim.x + t; g < ngrp; g += stride) {
        const iv4* pii = reinterpret_cast<const iv4*>(idx_i) + 2 * g;
        const iv4* pjj = reinterpret_cast<const iv4*>(idx_j) + 2 * g;
        const fv4* pdd = reinterpret_cast<const fv4*>(d_ij) + 2 * g;
        // Non-temporal stream loads: don't evict the 4MB gather table from L2.
        iv4 ii0 = __builtin_nontemporal_load(pii);
        iv4 ii1 = __builtin_nontemporal_load(pii + 1);
        iv4 jj0 = __builtin_nontemporal_load(pjj);
        iv4 jj1 = __builtin_nontemporal_load(pjj + 1);
        fv4 dd0 = __builtin_nontemporal_load(pdd);
        fv4 dd1 = __builtin_nontemporal_load(pdd + 1);

        int ia[8], ja[8];
        float da[8];
#pragma unroll
        for (int k = 0; k < 4; ++k) {
            ia[k] = ii0[k]; ia[4 + k] = ii1[k];
            ja[k] = jj0[k]; ja[4 + k] = jj1[k];
            da[k] = dd0[k]; da[4 + k] = dd1[k];
        }

        // Phase 1: issue ALL 16 gathers back-to-back (no control flow between
        // them). Masked-out lanes read packed[0] — a single always-hot line.
        unsigned int pia[8], pja[8];
#pragma unroll
        for (int k = 0; k < 8; ++k) {
            bool m = ia[k] < ja[k];
            pia[k] = packed[m ? ia[k] : 0];
            pja[k] = packed[m ? ja[k] : 0];
        }

        // Phase 2: compute + LDS accumulate.
#pragma unroll
        for (int k = 0; k < 8; ++k) {
            if (ia[k] < ja[k]) {
                int zi = (int)(pia[k] & 0xFFu);
                int zj = (int)(pja[k] & 0xFFu);
                int seg = (int)(pia[k] >> 8);
                bool pass;
                float e = zbl_energy(zi, zj, da[k], s_r, s_zp, pass);
                if (pass) atomicAdd(&s_hist[seg], e);
            }
        }
    }

    // Tail (n_edges % 8 != 0): at most 7 edges, one thread handles them.
    if (blockIdx.x == 0 && t == 0) {
        for (int e = ngrp << 3; e < n_edges; ++e) {
            int i = idx_i[e], j = idx_j[e];
            if (i < j) {
                unsigned int pi = packed[i], pj = packed[j];
                bool pass;
                float en = zbl_energy((int)(pi & 0xFFu), (int)(pj & 0xFFu),
                                      d_ij[e], s_r, s_zp, pass);
                if (pass) atomicAdd(&s_hist[(int)(pi >> 8)], en);
            }
        }
    }

    __syncthreads();
    // Flush histogram to this block's replica row. Regular stores: rep is
    // read immediately by reduce1 — keep it in L2.
    fv4* __restrict__ rp =
        reinterpret_cast<fv4*>(rep + (size_t)blockIdx.x * NBINS_PAD);
    const fv4* sh = reinterpret_cast<const fv4*>(s_hist);
    for (int q = t; q < NBINS_PAD / 4; q += 1024)
        rp[q] = sh[q];
}

// Stage 1: partial[s][bin] = sum over replica rows r = s, s+NPART, ...
__global__ __launch_bounds__(256)
void reduce1_kernel(const float* __restrict__ rep,
                    float* __restrict__ partial) {
    int bin = blockIdx.x * 256 + threadIdx.x;
    int s = blockIdx.y;
    float acc = 0.0f;
    for (int r = s; r < NREP; r += NPART)
        acc += rep[(size_t)r * NBINS_PAD + bin];
    partial[(size_t)s * NBINS_PAD + bin] = acc;
}

// Stage 2: out[bin] = sum over NPART partials. Writes every bin (no zero pass).
__global__ __launch_bounds__(256)
void reduce2_kernel(const float* __restrict__ partial,
                    float* __restrict__ out, int out_size) {
    int bin = blockIdx.x * 256 + threadIdx.x;
    if (bin < out_size) {
        float acc = 0.0f;
        for (int s = 0; s < NPART; ++s)
            acc += partial[(size_t)s * NBINS_PAD + bin];
        out[bin] = acc;
    }
}

// ---------------- fallback path (R1): direct global atomics ----------------

template <bool PACKED>
__global__ __launch_bounds__(256)
void zbl_atomic_kernel(const float* __restrict__ d_ij,
                       const float* __restrict__ radii,
                       const int* __restrict__ idx_i,
                       const int* __restrict__ idx_j,
                       const unsigned int* __restrict__ packed,
                       const int* __restrict__ atomz,
                       const int* __restrict__ subsys,
                       float* __restrict__ out,
                       int nchunk) {
    __shared__ float s_r[128];
    __shared__ float s_zp[128];
    int t = threadIdx.x;
    if (t < 128) {
        s_r[t] = (t < MAXZ) ? radii[t] : 0.0f;
        s_zp[t] = __builtin_exp2f(0.23f * __builtin_log2f((float)t));
    }
    __syncthreads();

    int chunk = blockIdx.x * blockDim.x + threadIdx.x;
    if (chunk >= nchunk) return;

    iv4 ii = reinterpret_cast<const iv4*>(idx_i)[chunk];
    iv4 jj = reinterpret_cast<const iv4*>(idx_j)[chunk];
    fv4 dd = reinterpret_cast<const fv4*>(d_ij)[chunk];

#pragma unroll
    for (int k = 0; k < 4; ++k) {
        int i = ii[k];
        int j = jj[k];
        float d = dd[k];
        if (i < j) {
            int zi, zj, seg;
            if (PACKED) {
                unsigned int pi = packed[i];
                unsigned int pj = packed[j];
                zi = (int)(pi & 0xFFu);
                zj = (int)(pj & 0xFFu);
                seg = (int)(pi >> 8);
            } else {
                zi = atomz[i];
                zj = atomz[j];
                seg = subsys[i];
            }
            bool pass;
            float e = zbl_energy(zi, zj, d, s_r, s_zp, pass);
            if (pass) atomicAdd(out + seg, e);
        }
    }
}

extern "C" void kernel_launch(void* const* d_in, const int* in_sizes, int n_in,
                              void* d_out, int out_size, void* d_ws, size_t ws_size,
                              hipStream_t stream) {
    const float* d_ij  = (const float*)d_in[0];
    const float* radii = (const float*)d_in[1];
    const int* pairs   = (const int*)d_in[2];
    const int* atomz   = (const int*)d_in[3];
    const int* subsys  = (const int*)d_in[4];
    float* out = (float*)d_out;

    const int n_edges = in_sizes[2] / 2;   // 16,000,000
    const int n_atoms = in_sizes[3];       // 1,000,000
    const int* idx_i = pairs;
    const int* idx_j = pairs + n_edges;

    const size_t packed_bytes = (size_t)n_atoms * sizeof(unsigned int);
    const size_t rep_bytes = (size_t)NREP * NBINS_PAD * sizeof(float);
    const size_t part_bytes = (size_t)NPART * NBINS_PAD * sizeof(float);

    if (ws_size >= packed_bytes + rep_bytes + part_bytes) {
        unsigned int* packed = (unsigned int*)d_ws;
        float* rep = (float*)((char*)d_ws + packed_bytes);
        float* partial = (float*)((char*)d_ws + packed_bytes + rep_bytes);

        pack_kernel<<<(n_atoms + 255) / 256, 256, 0, stream>>>(atomz, subsys,
                                                               packed, n_atoms);
        zbl_hist_kernel<<<NREP, 1024, 0, stream>>>(
            d_ij, radii, idx_i, idx_j, packed, rep, n_edges);
        dim3 g1(NBINS_PAD / 256, NPART);
        reduce1_kernel<<<g1, 256, 0, stream>>>(rep, partial);
        reduce2_kernel<<<(out_size + 255) / 256, 256, 0, stream>>>(
            partial, out, out_size);
    } else {
        // Fallback: direct-atomic path (R1)
        zero_kernel<<<(out_size + 255) / 256, 256, 0, stream>>>(out, out_size);
        const int nchunk = n_edges / 4;
        const int blocks = (nchunk + 255) / 256;
        if (ws_size >= packed_bytes) {
            unsigned int* packed = (unsigned int*)d_ws;
            pack_kernel<<<(n_atoms + 255) / 256, 256, 0, stream>>>(
                atomz, subsys, packed, n_atoms);
            zbl_atomic_kernel<true><<<blocks, 256, 0, stream>>>(
                d_ij, radii, idx_i, idx_j, packed, atomz, subsys, out, nchunk);
        } else {
            zbl_atomic_kernel<false><<<blocks, 256, 0, stream>>>(
                d_ij, radii, idx_i, idx_j, nullptr, atomz, subsys, out, nchunk);
        }
    }
}